// Round 1
// 2722.330 us; speedup vs baseline: 3.1686x; 3.1686x over previous
//
#include <hip/hip_runtime.h>

typedef unsigned short u16;
typedef unsigned int   u32;
typedef __attribute__((ext_vector_type(4))) u16   u16x4;
typedef __attribute__((ext_vector_type(8))) u16   u16x8;
typedef __attribute__((ext_vector_type(8))) __bf16 bf16x8;
typedef __attribute__((ext_vector_type(4))) float  floatx4;
typedef __attribute__((ext_vector_type(4))) u32   u32x4;

#define TT 512   // seq len
#define BB 64    // batch
#define HD 512   // hidden/emb dim
#define SENT 0xAAAAAAAAu

// ---------- helpers ----------
__device__ __forceinline__ u16 f2bf(float f) {
  u32 u = __builtin_bit_cast(u32, f);
  u32 r = u + 0x7fffu + ((u >> 16) & 1u);   // round-to-nearest-even
  return (u16)(r >> 16);
}
__device__ __forceinline__ float bf2f(u16 h) {
  return __builtin_bit_cast(float, ((u32)h) << 16);
}
__device__ __forceinline__ float fast_tanh(float x) {
  float xc = fminf(fmaxf(x, -12.f), 12.f);
  float e = __expf(2.f * xc);
  return __fdividef(e - 1.f, e + 1.f);
}

// ---------- prep: convert weights to bf16, sum biases ----------
// wbf layout: [wih0 | whh0 | wih1 | whh1], each 512*512
__global__ __launch_bounds__(256)
void prep_kernel(const float* __restrict__ W_ih, const float* __restrict__ W_hh,
                 const float* __restrict__ b_ih, const float* __restrict__ b_hh,
                 u16* __restrict__ wbf, float* __restrict__ bsum) {
  int idx = blockIdx.x * blockDim.x + threadIdx.x;
  int stride = gridDim.x * blockDim.x;
  for (int i = idx; i < 4 * 262144; i += stride) {
    int mat = i >> 18;
    int off = i & 262143;
    const float* src = (mat == 0) ? W_ih : (mat == 1) ? W_hh
                     : (mat == 2) ? (W_ih + 262144) : (W_hh + 262144);
    wbf[i] = f2bf(src[off]);
  }
  if (idx < 1024) bsum[idx] = b_ih[idx] + b_hh[idx];
}

// ---------- pre-activation GEMM ----------
// Xpre[m][n] = A[m][:] @ W[n][:] + bsum[n],  M=T*B (m = t*64+b), K=512, N=512
// mode 0: A row = emb[x[b][t]] (fp32, cvt to bf16)
// mode 1: A row = hist[t+1][b][0:512] low 16 bits (hi bf16 of h0)
__global__ __launch_bounds__(256, 2)
void gemm_pre(const u16* __restrict__ Bw, const float* __restrict__ bsum,
              const float* __restrict__ embsrc, const int* __restrict__ xtok,
              const u32* __restrict__ hist, float* __restrict__ Xpre, int mode) {
  __shared__ u16 As[128][40];
  __shared__ u16 Bs[128][40];
  const int tid = threadIdx.x;
  const int wave = tid >> 6, lane = tid & 63;
  const int quad = lane >> 4, l16 = lane & 15;
  const int mtile = blockIdx.x >> 2, ntile = blockIdx.x & 3;
  const int m0 = mtile * 128, n0 = ntile * 128;
  const int srow = tid >> 1, half = tid & 1;

  const float* aF = nullptr; const u32* aU = nullptr;
  {
    const int grow = m0 + srow;
    if (mode == 0) {
      const int t = grow >> 6, b = grow & 63;
      const int tok = xtok[b * TT + t];
      aF = embsrc + (size_t)tok * 512 + half * 16;
    } else {
      aU = hist + (size_t)((grow >> 6) + 1) * 32768 + (size_t)(grow & 63) * 512 + half * 16;
    }
  }
  const u16* bptr = Bw + (size_t)(n0 + srow) * 512 + half * 16;

  floatx4 acc[2][8];
#pragma unroll
  for (int a = 0; a < 2; a++)
#pragma unroll
    for (int b = 0; b < 8; b++) acc[a][b] = (floatx4){0.f, 0.f, 0.f, 0.f};

  for (int ks = 0; ks < 16; ks++) {
    const int k0 = ks * 32;
    u32 packed[8];
    if (mode == 0) {
      const float4* p = (const float4*)(aF + k0);
      float4 f0 = p[0], f1 = p[1], f2 = p[2], f3 = p[3];
      float vals[16] = {f0.x, f0.y, f0.z, f0.w, f1.x, f1.y, f1.z, f1.w,
                        f2.x, f2.y, f2.z, f2.w, f3.x, f3.y, f3.z, f3.w};
#pragma unroll
      for (int j = 0; j < 8; j++)
        packed[j] = (u32)f2bf(vals[2 * j]) | ((u32)f2bf(vals[2 * j + 1]) << 16);
    } else {
      const u32x4* p = (const u32x4*)(aU + k0);
      u32x4 q0 = p[0], q1 = p[1], q2 = p[2], q3 = p[3];
      u32 w[16] = {q0[0], q0[1], q0[2], q0[3], q1[0], q1[1], q1[2], q1[3],
                   q2[0], q2[1], q2[2], q2[3], q3[0], q3[1], q3[2], q3[3]};
#pragma unroll
      for (int j = 0; j < 8; j++)
        packed[j] = (w[2 * j] & 0xffffu) | ((w[2 * j + 1] & 0xffffu) << 16);
    }
    {
      u32x4* adst = (u32x4*)&As[srow][half * 16];
      adst[0] = (u32x4){packed[0], packed[1], packed[2], packed[3]};
      adst[1] = (u32x4){packed[4], packed[5], packed[6], packed[7]};
    }
    {
      const u32x4* bp = (const u32x4*)(bptr + k0);
      u32x4 b0 = bp[0], b1 = bp[1];
      u32x4* bdst = (u32x4*)&Bs[srow][half * 16];
      bdst[0] = b0; bdst[1] = b1;
    }
    __syncthreads();
    bf16x8 afr[2], bfr[8];
#pragma unroll
    for (int mt = 0; mt < 2; mt++)
      afr[mt] = __builtin_bit_cast(bf16x8, *(const u16x8*)&As[wave * 32 + mt * 16 + l16][quad * 8]);
#pragma unroll
    for (int nt = 0; nt < 8; nt++)
      bfr[nt] = __builtin_bit_cast(bf16x8, *(const u16x8*)&Bs[nt * 16 + l16][quad * 8]);
#pragma unroll
    for (int mt = 0; mt < 2; mt++)
#pragma unroll
      for (int nt = 0; nt < 8; nt++)
        acc[mt][nt] = __builtin_amdgcn_mfma_f32_16x16x32_bf16(afr[mt], bfr[nt], acc[mt][nt], 0, 0, 0);
    __syncthreads();
  }
  float bs[8];
#pragma unroll
  for (int nt = 0; nt < 8; nt++) bs[nt] = bsum[n0 + nt * 16 + l16];
#pragma unroll
  for (int mt = 0; mt < 2; mt++)
#pragma unroll
    for (int nt = 0; nt < 8; nt++)
#pragma unroll
      for (int i = 0; i < 4; i++) {
        const int gm = m0 + wave * 32 + mt * 16 + quad * 4 + i;
        Xpre[(size_t)gm * 512 + n0 + nt * 16 + l16] = acc[mt][nt][i] + bs[nt];
      }
}

// ---------- sequential recurrence pass (one layer) ----------
// 32 wgs: c = blockIdx>>2 (column slice of 64), g = blockIdx&3 (batch tile of 16)
// hist slot s holds h(s-1) as u32/element: lo16 = bf16 hi part, hi16 = bf16 lo part.
// Every word is SELF-VALIDATING: slots pre-poisoned to SENT; producers publish
// with relaxed agent atomic stores, consumers poll each word for != SENT.
// POLL IS BATCHED: each sweep re-issues ALL pending loads back-to-back so a
// sweep costs ~1 memory round-trip, not one round-trip per pending word.
__global__ __launch_bounds__(256, 1)
void rnn_pass(const u16* __restrict__ Whh, const float* __restrict__ Xpre,
              u32* __restrict__ hist, const int* __restrict__ lengths,
              float* __restrict__ out_last, float* __restrict__ out_hidden) {
  __shared__ u32 Abuf[2][16][512];   // double-buffered, XOR-swizzled (no padding)
  const int tid = threadIdx.x;
  const int wave = tid >> 6, lane = tid & 63;
  const int quad = lane >> 4, l16 = lane & 15;
  const int c = blockIdx.x >> 2, g = blockIdx.x & 3;
  const int mycol = c * 64 + wave * 16 + l16;
  const int w4 = wave * 4;           // staging rows for this wave

  // preload W_hh slice into registers as duplicated B-fragments (K'=1024)
  bf16x8 wfrag[32];
  {
    const u16* wrow = Whh + (size_t)mycol * 512 + quad * 4;
#pragma unroll
    for (int s = 0; s < 32; s++) {
      u16x4 w4v = *(const u16x4*)(wrow + s * 16);
      u16x8 w8 = {w4v[0], w4v[0], w4v[1], w4v[1], w4v[2], w4v[2], w4v[3], w4v[3]};
      wfrag[s] = __builtin_bit_cast(bf16x8, w8);
    }
  }
  float hcur[4];
  int lens[4];
#pragma unroll
  for (int i = 0; i < 4; i++) {
    hcur[i] = 0.f;
    lens[i] = lengths[g * 16 + quad * 4 + i];
  }
  const int xswr = (l16 & 7) << 2;   // fragment-read swizzle for this lane

  for (int t = 0; t < TT; t++) {
    const int buf = t & 1;
    // prefetch pre-activations (independent of exchange)
    float pre[4];
#pragma unroll
    for (int i = 0; i < 4; i++)
      pre[i] = Xpre[(size_t)t * 32768 + (size_t)(g * 16 + quad * 4 + i) * 512 + mycol];

    // ---- poll + stage h(t-1): wave handles rows w4..w4+3, coalesced 256B runs
    u32 v[32];
    const u32* sbase = hist + (size_t)t * 32768 + (size_t)(g * 16 + w4) * 512 + lane;
#pragma unroll
    for (int j = 0; j < 32; j++)
      v[j] = __hip_atomic_load(sbase + (j >> 3) * 512 + (j & 7) * 64,
                               __ATOMIC_RELAXED, __HIP_MEMORY_SCOPE_AGENT);
    {
      // batched sweeps: re-load all 32 words in parallel (independent relaxed
      // atomics -> 32 global_loads in flight, one waitcnt), then re-check.
      int guard = 0;
      while (true) {
        u32 pend = 0;
#pragma unroll
        for (int j = 0; j < 32; j++) pend |= (u32)(v[j] == SENT);
        if (__builtin_expect(pend == 0u, 1)) break;
        if (++guard > (1 << 16)) break;   // terminate rather than hang
        __builtin_amdgcn_s_sleep(1);
#pragma unroll
        for (int j = 0; j < 32; j++)
          v[j] = __hip_atomic_load(sbase + (j >> 3) * 512 + (j & 7) * 64,
                                   __ATOMIC_RELAXED, __HIP_MEMORY_SCOPE_AGENT);
      }
    }
#pragma unroll
    for (int rr = 0; rr < 4; rr++) {
      const int row = w4 + rr;
      u32* wrow = &Abuf[buf][row][0];
      const int xsw = (row & 7) << 2;
#pragma unroll
      for (int k = 0; k < 8; k++)
        wrow[(k * 64 + lane) ^ xsw] = v[rr * 8 + k];
    }
    __syncthreads();   // single barrier per step (double-buffered LDS)

    // ---- MFMA: D(16x16) += A(16 x K'=1024) * Wdup, 4 independent chains
    floatx4 ac[4];
#pragma unroll
    for (int q = 0; q < 4; q++) ac[q] = (floatx4){0.f, 0.f, 0.f, 0.f};
    const u32* arow = &Abuf[buf][l16][0];
#pragma unroll
    for (int s = 0; s < 32; s += 4) {
#pragma unroll
      for (int q = 0; q < 4; q++) {
        bf16x8 a = __builtin_bit_cast(bf16x8,
            *(const u16x8*)(arow + (((s + q) * 16 + quad * 4) ^ xswr)));
        ac[q] = __builtin_amdgcn_mfma_f32_16x16x32_bf16(a, wfrag[s + q], ac[q], 0, 0, 0);
      }
    }

    // ---- epilogue: tanh + mask + publish h(t) words (self-validating)
#pragma unroll
    for (int i = 0; i < 4; i++) {
      const float vsum = ac[0][i] + ac[1][i] + ac[2][i] + ac[3][i] + pre[i];
      const float th = fast_tanh(vsum);
      const float nv = (t < lens[i]) ? th : hcur[i];
      hcur[i] = nv;
      const u16 hi = f2bf(nv);
      const u16 lo = f2bf(nv - bf2f(hi));
      u32 wv = (u32)hi | ((u32)lo << 16);
      wv += (wv == SENT);   // exclude sentinel (1 ulp of lo correction)
      __hip_atomic_store(hist + (size_t)(t + 1) * 32768 +
                             (size_t)(g * 16 + quad * 4 + i) * 512 + mycol,
                         wv, __ATOMIC_RELAXED, __HIP_MEMORY_SCOPE_AGENT);
    }
  }
  // final hidden state (fp32 registers, post-mask)
#pragma unroll
  for (int i = 0; i < 4; i++) {
    const int b = g * 16 + quad * 4 + i;
    if (out_hidden) out_hidden[(size_t)b * 1024 + mycol] = hcur[i];
    if (out_last)   out_last[(size_t)b * 512 + mycol] = hcur[i];
  }
}

// ---------- launch ----------
extern "C" void kernel_launch(void* const* d_in, const int* in_sizes, int n_in,
                              void* d_out, int out_size, void* d_ws, size_t ws_size,
                              hipStream_t stream) {
  const int*   x   = (const int*)d_in[0];
  const int*   len = (const int*)d_in[1];
  const float* emb = (const float*)d_in[2];
  const float* Wih = (const float*)d_in[3];
  const float* Whh = (const float*)d_in[4];
  const float* bih = (const float*)d_in[5];
  const float* bhh = (const float*)d_in[6];
  float* out = (float*)d_out;

  char* ws = (char*)d_ws;
  float* Xpre  = (float*)(ws);                   // 67,108,864 B (T*B*512 fp32), reused for both layers
  u32*   hist  = (u32*)(ws + 67108864);          // 67,239,936 B ((T+1)*B*512 u32), reused for both layers
  u16*   wbf   = (u16*)(ws + 134348800);         // 2,097,152 B
  float* bsum  = (float*)(ws + 136445952);       // 4,096 B

  // slot 0 = h(-1) = 0 (valid zeros); slots 1..512 = sentinel poison
  hipMemsetAsync(hist, 0, 131072, stream);
  hipMemsetAsync((char*)hist + 131072, 0xAA, (size_t)512 * 131072, stream);
  hipLaunchKernelGGL(prep_kernel, dim3(512), dim3(256), 0, stream, Wih, Whh, bih, bhh, wbf, bsum);
  // layer 0 pre: emb gather GEMM
  hipLaunchKernelGGL(gemm_pre, dim3(1024), dim3(256), 0, stream,
                     wbf /*wih0*/, bsum, emb, x, (const u32*)nullptr, Xpre, 0);
  // layer 0 recurrence
  hipLaunchKernelGGL(rnn_pass, dim3(32), dim3(256), 0, stream,
                     wbf + 262144 /*whh0*/, Xpre, hist, len,
                     (float*)nullptr, out + 32768 /*hidden[:,0,:]*/);
  // layer 1 pre: h0 history GEMM (reads hist slots 1..512)
  hipLaunchKernelGGL(gemm_pre, dim3(1024), dim3(256), 0, stream,
                     wbf + 524288 /*wih1*/, bsum + 512, (const float*)nullptr, (const int*)nullptr,
                     hist, Xpre, 1);
  // re-poison hist slots 1..512 for pass 2 (after gemm_pre consumed them)
  hipMemsetAsync((char*)hist + 131072, 0xAA, (size_t)512 * 131072, stream);
  // layer 1 recurrence
  hipLaunchKernelGGL(rnn_pass, dim3(32), dim3(256), 0, stream,
                     wbf + 786432 /*whh1*/, Xpre, hist, len,
                     out /*h_last*/, out + 32768 + 512 /*hidden[:,1,:]*/);
}

// Round 2
// 2383.441 us; speedup vs baseline: 3.6191x; 1.1422x over previous
//
#include <hip/hip_runtime.h>

typedef unsigned short u16;
typedef unsigned int   u32;
typedef __attribute__((ext_vector_type(4))) u16   u16x4;
typedef __attribute__((ext_vector_type(8))) u16   u16x8;
typedef __attribute__((ext_vector_type(8))) __bf16 bf16x8;
typedef __attribute__((ext_vector_type(4))) float  floatx4;
typedef __attribute__((ext_vector_type(4))) u32   u32x4;

#define TT 512   // seq len
#define BB 64    // batch
#define HD 512   // hidden/emb dim
#define SENT 0xAAAAAAAAu

// ---------- helpers ----------
__device__ __forceinline__ u16 f2bf(float f) {
  u32 u = __builtin_bit_cast(u32, f);
  u32 r = u + 0x7fffu + ((u >> 16) & 1u);   // round-to-nearest-even
  return (u16)(r >> 16);
}
__device__ __forceinline__ float bf2f(u16 h) {
  return __builtin_bit_cast(float, ((u32)h) << 16);
}
__device__ __forceinline__ float fast_tanh(float x) {
  float xc = fminf(fmaxf(x, -12.f), 12.f);
  float e = __expf(2.f * xc);
  return __fdividef(e - 1.f, e + 1.f);
}

// ---------- prep: convert weights to bf16, sum biases ----------
// wbf layout: [wih0 | whh0 | wih1 | whh1], each 512*512
__global__ __launch_bounds__(256)
void prep_kernel(const float* __restrict__ W_ih, const float* __restrict__ W_hh,
                 const float* __restrict__ b_ih, const float* __restrict__ b_hh,
                 u16* __restrict__ wbf, float* __restrict__ bsum) {
  int idx = blockIdx.x * blockDim.x + threadIdx.x;
  int stride = gridDim.x * blockDim.x;
  for (int i = idx; i < 4 * 262144; i += stride) {
    int mat = i >> 18;
    int off = i & 262143;
    const float* src = (mat == 0) ? W_ih : (mat == 1) ? W_hh
                     : (mat == 2) ? (W_ih + 262144) : (W_hh + 262144);
    wbf[i] = f2bf(src[off]);
  }
  if (idx < 1024) bsum[idx] = b_ih[idx] + b_hh[idx];
}

// ---------- pre-activation GEMM ----------
// Xpre[m][n] = A[m][:] @ W[n][:] + bsum[n],  M=T*B (m = t*64+b), K=512, N=512
// mode 0: A row = emb[x[b][t]] (fp32, cvt to bf16)
// mode 1: A row = hist[t+1][b][0:512] low 16 bits (hi bf16 of h0)  [fallback only]
__global__ __launch_bounds__(256, 2)
void gemm_pre(const u16* __restrict__ Bw, const float* __restrict__ bsum,
              const float* __restrict__ embsrc, const int* __restrict__ xtok,
              const u32* __restrict__ hist, float* __restrict__ Xpre, int mode) {
  __shared__ u16 As[128][40];
  __shared__ u16 Bs[128][40];
  const int tid = threadIdx.x;
  const int wave = tid >> 6, lane = tid & 63;
  const int quad = lane >> 4, l16 = lane & 15;
  const int mtile = blockIdx.x >> 2, ntile = blockIdx.x & 3;
  const int m0 = mtile * 128, n0 = ntile * 128;
  const int srow = tid >> 1, half = tid & 1;

  const float* aF = nullptr; const u32* aU = nullptr;
  {
    const int grow = m0 + srow;
    if (mode == 0) {
      const int t = grow >> 6, b = grow & 63;
      const int tok = xtok[b * TT + t];
      aF = embsrc + (size_t)tok * 512 + half * 16;
    } else {
      aU = hist + (size_t)((grow >> 6) + 1) * 32768 + (size_t)(grow & 63) * 512 + half * 16;
    }
  }
  const u16* bptr = Bw + (size_t)(n0 + srow) * 512 + half * 16;

  floatx4 acc[2][8];
#pragma unroll
  for (int a = 0; a < 2; a++)
#pragma unroll
    for (int b = 0; b < 8; b++) acc[a][b] = (floatx4){0.f, 0.f, 0.f, 0.f};

  for (int ks = 0; ks < 16; ks++) {
    const int k0 = ks * 32;
    u32 packed[8];
    if (mode == 0) {
      const float4* p = (const float4*)(aF + k0);
      float4 f0 = p[0], f1 = p[1], f2 = p[2], f3 = p[3];
      float vals[16] = {f0.x, f0.y, f0.z, f0.w, f1.x, f1.y, f1.z, f1.w,
                        f2.x, f2.y, f2.z, f2.w, f3.x, f3.y, f3.z, f3.w};
#pragma unroll
      for (int j = 0; j < 8; j++)
        packed[j] = (u32)f2bf(vals[2 * j]) | ((u32)f2bf(vals[2 * j + 1]) << 16);
    } else {
      const u32x4* p = (const u32x4*)(aU + k0);
      u32x4 q0 = p[0], q1 = p[1], q2 = p[2], q3 = p[3];
      u32 w[16] = {q0[0], q0[1], q0[2], q0[3], q1[0], q1[1], q1[2], q1[3],
                   q2[0], q2[1], q2[2], q2[3], q3[0], q3[1], q3[2], q3[3]};
#pragma unroll
      for (int j = 0; j < 8; j++)
        packed[j] = (w[2 * j] & 0xffffu) | ((w[2 * j + 1] & 0xffffu) << 16);
    }
    {
      u32x4* adst = (u32x4*)&As[srow][half * 16];
      adst[0] = (u32x4){packed[0], packed[1], packed[2], packed[3]};
      adst[1] = (u32x4){packed[4], packed[5], packed[6], packed[7]};
    }
    {
      const u32x4* bp = (const u32x4*)(bptr + k0);
      u32x4 b0 = bp[0], b1 = bp[1];
      u32x4* bdst = (u32x4*)&Bs[srow][half * 16];
      bdst[0] = b0; bdst[1] = b1;
    }
    __syncthreads();
    bf16x8 afr[2], bfr[8];
#pragma unroll
    for (int mt = 0; mt < 2; mt++)
      afr[mt] = __builtin_bit_cast(bf16x8, *(const u16x8*)&As[wave * 32 + mt * 16 + l16][quad * 8]);
#pragma unroll
    for (int nt = 0; nt < 8; nt++)
      bfr[nt] = __builtin_bit_cast(bf16x8, *(const u16x8*)&Bs[nt * 16 + l16][quad * 8]);
#pragma unroll
    for (int mt = 0; mt < 2; mt++)
#pragma unroll
      for (int nt = 0; nt < 8; nt++)
        acc[mt][nt] = __builtin_amdgcn_mfma_f32_16x16x32_bf16(afr[mt], bfr[nt], acc[mt][nt], 0, 0, 0);
    __syncthreads();
  }
  float bs[8];
#pragma unroll
  for (int nt = 0; nt < 8; nt++) bs[nt] = bsum[n0 + nt * 16 + l16];
#pragma unroll
  for (int mt = 0; mt < 2; mt++)
#pragma unroll
    for (int nt = 0; nt < 8; nt++)
#pragma unroll
      for (int i = 0; i < 4; i++) {
        const int gm = m0 + wave * 32 + mt * 16 + quad * 4 + i;
        Xpre[(size_t)gm * 512 + n0 + nt * 16 + l16] = acc[mt][nt][i] + bs[nt];
      }
}

// ---------- FUSED two-layer recurrence, layer-pipelined ----------
// 64 WGs in ONE launch (all co-resident: 1 WG/CU at 128KiB LDS, 256 CUs).
//   blocks  0..31: layer 0  (identical protocol to the proven rnn_pass)
//   blocks 32..63: layer 1, runs one pipeline stage behind layer 0:
//       h1(t) = tanh( h0(t) @ Wih1^T + h1(t-1) @ Whh1^T + bsum1 )
//     polls h0(t) from hist0[t+1] (published by layer-0 epilogue) and
//     h1(t-1) from hist1[t]. Same self-validating sentinel protocol,
//     batched sweeps over all 64 words.
// Both matmuls use dual-bf16 (hi+lo) A operands -> >= previous accuracy.
__global__ __launch_bounds__(256, 1)
void rnn_fused(const u16* __restrict__ wbf, const float* __restrict__ bsum,
               const float* __restrict__ Xpre, u32* __restrict__ hist0,
               u32* __restrict__ hist1, const int* __restrict__ lengths,
               float* __restrict__ out) {
  __shared__ u32 smem[2][32][512];   // 128 KiB; layer0 uses rows 0..15 only
  const int tid = threadIdx.x;
  const int wave = tid >> 6, lane = tid & 63;
  const int quad = lane >> 4, l16 = lane & 15;
  const int bid = blockIdx.x;
  const int layer = bid >> 5;
  const int rr_ = bid & 31;
  const int c = rr_ >> 2, g = rr_ & 3;
  const int mycol = c * 64 + wave * 16 + l16;
  const int w4 = wave * 4;
  const int xswr = (l16 & 7) << 2;

  float hcur[4];
  int lens[4];
#pragma unroll
  for (int i = 0; i < 4; i++) {
    hcur[i] = 0.f;
    lens[i] = lengths[g * 16 + quad * 4 + i];
  }

  if (layer == 0) {
    // ================= layer 0 =================
    const u16* Whh = wbf + 262144;
    bf16x8 wfrag[32];
    {
      const u16* wrow = Whh + (size_t)mycol * 512 + quad * 4;
#pragma unroll
      for (int s = 0; s < 32; s++) {
        u16x4 w4v = *(const u16x4*)(wrow + s * 16);
        u16x8 w8 = {w4v[0], w4v[0], w4v[1], w4v[1], w4v[2], w4v[2], w4v[3], w4v[3]};
        wfrag[s] = __builtin_bit_cast(bf16x8, w8);
      }
    }
    for (int t = 0; t < TT; t++) {
      const int buf = t & 1;
      float pre[4];
#pragma unroll
      for (int i = 0; i < 4; i++)
        pre[i] = Xpre[(size_t)t * 32768 + (size_t)(g * 16 + quad * 4 + i) * 512 + mycol];

      u32 v[32];
      const u32* sbase = hist0 + (size_t)t * 32768 + (size_t)(g * 16 + w4) * 512 + lane;
#pragma unroll
      for (int j = 0; j < 32; j++)
        v[j] = __hip_atomic_load(sbase + (j >> 3) * 512 + (j & 7) * 64,
                                 __ATOMIC_RELAXED, __HIP_MEMORY_SCOPE_AGENT);
      {
        int guard = 0;
        while (true) {
          u32 pend = 0;
#pragma unroll
          for (int j = 0; j < 32; j++) pend |= (u32)(v[j] == SENT);
          if (__builtin_expect(pend == 0u, 1)) break;
          if (++guard > (1 << 16)) break;
          __builtin_amdgcn_s_sleep(1);
#pragma unroll
          for (int j = 0; j < 32; j++)
            v[j] = __hip_atomic_load(sbase + (j >> 3) * 512 + (j & 7) * 64,
                                     __ATOMIC_RELAXED, __HIP_MEMORY_SCOPE_AGENT);
        }
      }
#pragma unroll
      for (int rr = 0; rr < 4; rr++) {
        const int row = w4 + rr;
        u32* wrow = &smem[buf][row][0];
        const int xsw = (row & 7) << 2;
#pragma unroll
        for (int k = 0; k < 8; k++)
          wrow[(k * 64 + lane) ^ xsw] = v[rr * 8 + k];
      }
      __syncthreads();

      floatx4 ac[4];
#pragma unroll
      for (int q = 0; q < 4; q++) ac[q] = (floatx4){0.f, 0.f, 0.f, 0.f};
      const u32* arow = &smem[buf][l16][0];
#pragma unroll
      for (int s = 0; s < 32; s += 4) {
#pragma unroll
        for (int q = 0; q < 4; q++) {
          bf16x8 a = __builtin_bit_cast(bf16x8,
              *(const u16x8*)(arow + (((s + q) * 16 + quad * 4) ^ xswr)));
          ac[q] = __builtin_amdgcn_mfma_f32_16x16x32_bf16(a, wfrag[s + q], ac[q], 0, 0, 0);
        }
      }

#pragma unroll
      for (int i = 0; i < 4; i++) {
        const float vsum = ac[0][i] + ac[1][i] + ac[2][i] + ac[3][i] + pre[i];
        const float th = fast_tanh(vsum);
        const float nv = (t < lens[i]) ? th : hcur[i];
        hcur[i] = nv;
        const u16 hi = f2bf(nv);
        const u16 lo = f2bf(nv - bf2f(hi));
        u32 wv = (u32)hi | ((u32)lo << 16);
        wv += (wv == SENT);
        __hip_atomic_store(hist0 + (size_t)(t + 1) * 32768 +
                               (size_t)(g * 16 + quad * 4 + i) * 512 + mycol,
                           wv, __ATOMIC_RELAXED, __HIP_MEMORY_SCOPE_AGENT);
      }
    }
#pragma unroll
    for (int i = 0; i < 4; i++) {
      const int b = g * 16 + quad * 4 + i;
      out[32768 + (size_t)b * 1024 + mycol] = hcur[i];   // hidden[:,0,:]
    }
  } else {
    // ================= layer 1 =================
    const u16* Wih = wbf + 524288;
    const u16* Whh = wbf + 786432;
    bf16x8 wfi[32], wfh[32];
    {
      const u16* wrow = Wih + (size_t)mycol * 512 + quad * 4;
#pragma unroll
      for (int s = 0; s < 32; s++) {
        u16x4 w4v = *(const u16x4*)(wrow + s * 16);
        u16x8 w8 = {w4v[0], w4v[0], w4v[1], w4v[1], w4v[2], w4v[2], w4v[3], w4v[3]};
        wfi[s] = __builtin_bit_cast(bf16x8, w8);
      }
    }
    {
      const u16* wrow = Whh + (size_t)mycol * 512 + quad * 4;
#pragma unroll
      for (int s = 0; s < 32; s++) {
        u16x4 w4v = *(const u16x4*)(wrow + s * 16);
        u16x8 w8 = {w4v[0], w4v[0], w4v[1], w4v[1], w4v[2], w4v[2], w4v[3], w4v[3]};
        wfh[s] = __builtin_bit_cast(bf16x8, w8);
      }
    }
    const float bs1 = bsum[512 + mycol];

    for (int t = 0; t < TT; t++) {
      const int buf = t & 1;
      u32 v0[32], v1[32];
      const u32* s0 = hist0 + (size_t)(t + 1) * 32768 + (size_t)(g * 16 + w4) * 512 + lane;
      const u32* s1 = hist1 + (size_t)t * 32768 + (size_t)(g * 16 + w4) * 512 + lane;
#pragma unroll
      for (int j = 0; j < 32; j++)
        v0[j] = __hip_atomic_load(s0 + (j >> 3) * 512 + (j & 7) * 64,
                                  __ATOMIC_RELAXED, __HIP_MEMORY_SCOPE_AGENT);
#pragma unroll
      for (int j = 0; j < 32; j++)
        v1[j] = __hip_atomic_load(s1 + (j >> 3) * 512 + (j & 7) * 64,
                                  __ATOMIC_RELAXED, __HIP_MEMORY_SCOPE_AGENT);
      {
        int guard = 0;
        while (true) {
          u32 pend = 0;
#pragma unroll
          for (int j = 0; j < 32; j++) pend |= (u32)(v0[j] == SENT) | (u32)(v1[j] == SENT);
          if (__builtin_expect(pend == 0u, 1)) break;
          if (++guard > (1 << 16)) break;
          __builtin_amdgcn_s_sleep(1);
#pragma unroll
          for (int j = 0; j < 32; j++)
            v0[j] = __hip_atomic_load(s0 + (j >> 3) * 512 + (j & 7) * 64,
                                      __ATOMIC_RELAXED, __HIP_MEMORY_SCOPE_AGENT);
#pragma unroll
          for (int j = 0; j < 32; j++)
            v1[j] = __hip_atomic_load(s1 + (j >> 3) * 512 + (j & 7) * 64,
                                      __ATOMIC_RELAXED, __HIP_MEMORY_SCOPE_AGENT);
        }
      }
#pragma unroll
      for (int rr = 0; rr < 4; rr++) {
        const int row = w4 + rr;
        const int xsw = (row & 7) << 2;
        u32* d0 = &smem[buf][row][0];
        u32* d1 = &smem[buf][16 + row][0];
#pragma unroll
        for (int k = 0; k < 8; k++) {
          d0[(k * 64 + lane) ^ xsw] = v0[rr * 8 + k];
          d1[(k * 64 + lane) ^ xsw] = v1[rr * 8 + k];
        }
      }
      __syncthreads();

      floatx4 ac[8];
#pragma unroll
      for (int q = 0; q < 8; q++) ac[q] = (floatx4){0.f, 0.f, 0.f, 0.f};
      const u32* a0 = &smem[buf][l16][0];
      const u32* a1 = &smem[buf][16 + l16][0];
#pragma unroll
      for (int s = 0; s < 32; s += 4) {
#pragma unroll
        for (int q = 0; q < 4; q++) {
          const int off = (((s + q) * 16 + quad * 4) ^ xswr);
          bf16x8 aa0 = __builtin_bit_cast(bf16x8, *(const u16x8*)(a0 + off));
          ac[q] = __builtin_amdgcn_mfma_f32_16x16x32_bf16(aa0, wfi[s + q], ac[q], 0, 0, 0);
          bf16x8 aa1 = __builtin_bit_cast(bf16x8, *(const u16x8*)(a1 + off));
          ac[4 + q] = __builtin_amdgcn_mfma_f32_16x16x32_bf16(aa1, wfh[s + q], ac[4 + q], 0, 0, 0);
        }
      }

#pragma unroll
      for (int i = 0; i < 4; i++) {
        const float vsum = ac[0][i] + ac[1][i] + ac[2][i] + ac[3][i] +
                           ac[4][i] + ac[5][i] + ac[6][i] + ac[7][i] + bs1;
        const float th = fast_tanh(vsum);
        const float nv = (t < lens[i]) ? th : hcur[i];
        hcur[i] = nv;
        const u16 hi = f2bf(nv);
        const u16 lo = f2bf(nv - bf2f(hi));
        u32 wv = (u32)hi | ((u32)lo << 16);
        wv += (wv == SENT);
        __hip_atomic_store(hist1 + (size_t)(t + 1) * 32768 +
                               (size_t)(g * 16 + quad * 4 + i) * 512 + mycol,
                           wv, __ATOMIC_RELAXED, __HIP_MEMORY_SCOPE_AGENT);
      }
    }
#pragma unroll
    for (int i = 0; i < 4; i++) {
      const int b = g * 16 + quad * 4 + i;
      out[(size_t)b * 512 + mycol] = hcur[i];                    // h_last
      out[32768 + (size_t)b * 1024 + 512 + mycol] = hcur[i];     // hidden[:,1,:]
    }
  }
}

// ---------- sequential recurrence pass (one layer) — FALLBACK only ----------
__global__ __launch_bounds__(256, 1)
void rnn_pass(const u16* __restrict__ Whh, const float* __restrict__ Xpre,
              u32* __restrict__ hist, const int* __restrict__ lengths,
              float* __restrict__ out_last, float* __restrict__ out_hidden) {
  __shared__ u32 Abuf[2][16][512];
  const int tid = threadIdx.x;
  const int wave = tid >> 6, lane = tid & 63;
  const int quad = lane >> 4, l16 = lane & 15;
  const int c = blockIdx.x >> 2, g = blockIdx.x & 3;
  const int mycol = c * 64 + wave * 16 + l16;
  const int w4 = wave * 4;

  bf16x8 wfrag[32];
  {
    const u16* wrow = Whh + (size_t)mycol * 512 + quad * 4;
#pragma unroll
    for (int s = 0; s < 32; s++) {
      u16x4 w4v = *(const u16x4*)(wrow + s * 16);
      u16x8 w8 = {w4v[0], w4v[0], w4v[1], w4v[1], w4v[2], w4v[2], w4v[3], w4v[3]};
      wfrag[s] = __builtin_bit_cast(bf16x8, w8);
    }
  }
  float hcur[4];
  int lens[4];
#pragma unroll
  for (int i = 0; i < 4; i++) {
    hcur[i] = 0.f;
    lens[i] = lengths[g * 16 + quad * 4 + i];
  }
  const int xswr = (l16 & 7) << 2;

  for (int t = 0; t < TT; t++) {
    const int buf = t & 1;
    float pre[4];
#pragma unroll
    for (int i = 0; i < 4; i++)
      pre[i] = Xpre[(size_t)t * 32768 + (size_t)(g * 16 + quad * 4 + i) * 512 + mycol];

    u32 v[32];
    const u32* sbase = hist + (size_t)t * 32768 + (size_t)(g * 16 + w4) * 512 + lane;
#pragma unroll
    for (int j = 0; j < 32; j++)
      v[j] = __hip_atomic_load(sbase + (j >> 3) * 512 + (j & 7) * 64,
                               __ATOMIC_RELAXED, __HIP_MEMORY_SCOPE_AGENT);
    {
      int guard = 0;
      while (true) {
        u32 pend = 0;
#pragma unroll
        for (int j = 0; j < 32; j++) pend |= (u32)(v[j] == SENT);
        if (__builtin_expect(pend == 0u, 1)) break;
        if (++guard > (1 << 16)) break;
        __builtin_amdgcn_s_sleep(1);
#pragma unroll
        for (int j = 0; j < 32; j++)
          v[j] = __hip_atomic_load(sbase + (j >> 3) * 512 + (j & 7) * 64,
                                   __ATOMIC_RELAXED, __HIP_MEMORY_SCOPE_AGENT);
      }
    }
#pragma unroll
    for (int rr = 0; rr < 4; rr++) {
      const int row = w4 + rr;
      u32* wrow = &Abuf[buf][row][0];
      const int xsw = (row & 7) << 2;
#pragma unroll
      for (int k = 0; k < 8; k++)
        wrow[(k * 64 + lane) ^ xsw] = v[rr * 8 + k];
    }
    __syncthreads();

    floatx4 ac[4];
#pragma unroll
    for (int q = 0; q < 4; q++) ac[q] = (floatx4){0.f, 0.f, 0.f, 0.f};
    const u32* arow = &Abuf[buf][l16][0];
#pragma unroll
    for (int s = 0; s < 32; s += 4) {
#pragma unroll
      for (int q = 0; q < 4; q++) {
        bf16x8 a = __builtin_bit_cast(bf16x8,
            *(const u16x8*)(arow + (((s + q) * 16 + quad * 4) ^ xswr)));
        ac[q] = __builtin_amdgcn_mfma_f32_16x16x32_bf16(a, wfrag[s + q], ac[q], 0, 0, 0);
      }
    }

#pragma unroll
    for (int i = 0; i < 4; i++) {
      const float vsum = ac[0][i] + ac[1][i] + ac[2][i] + ac[3][i] + pre[i];
      const float th = fast_tanh(vsum);
      const float nv = (t < lens[i]) ? th : hcur[i];
      hcur[i] = nv;
      const u16 hi = f2bf(nv);
      const u16 lo = f2bf(nv - bf2f(hi));
      u32 wv = (u32)hi | ((u32)lo << 16);
      wv += (wv == SENT);
      __hip_atomic_store(hist + (size_t)(t + 1) * 32768 +
                             (size_t)(g * 16 + quad * 4 + i) * 512 + mycol,
                         wv, __ATOMIC_RELAXED, __HIP_MEMORY_SCOPE_AGENT);
    }
  }
#pragma unroll
  for (int i = 0; i < 4; i++) {
    const int b = g * 16 + quad * 4 + i;
    if (out_hidden) out_hidden[(size_t)b * 1024 + mycol] = hcur[i];
    if (out_last)   out_last[(size_t)b * 512 + mycol] = hcur[i];
  }
}

// ---------- launch ----------
extern "C" void kernel_launch(void* const* d_in, const int* in_sizes, int n_in,
                              void* d_out, int out_size, void* d_ws, size_t ws_size,
                              hipStream_t stream) {
  const int*   x   = (const int*)d_in[0];
  const int*   len = (const int*)d_in[1];
  const float* emb = (const float*)d_in[2];
  const float* Wih = (const float*)d_in[3];
  const float* Whh = (const float*)d_in[4];
  const float* bih = (const float*)d_in[5];
  const float* bhh = (const float*)d_in[6];
  float* out = (float*)d_out;

  char* ws = (char*)d_ws;
  const size_t SZ_XPRE = 67108864;       // T*B*512 fp32
  const size_t SZ_HIST = 67239936;       // (T+1)*B*512 u32
  const size_t SZ_WBF  = 2097152;

  if (ws_size >= SZ_XPRE + 2 * SZ_HIST + SZ_WBF + 4096) {
    // ---------- fused layer-pipelined flow ----------
    float* Xpre  = (float*)(ws);
    u32*   hist0 = (u32*)(ws + SZ_XPRE);
    u32*   hist1 = (u32*)(ws + SZ_XPRE + SZ_HIST);
    u16*   wbf   = (u16*)(ws + SZ_XPRE + 2 * SZ_HIST);
    float* bsum  = (float*)(ws + SZ_XPRE + 2 * SZ_HIST + SZ_WBF);

    hipMemsetAsync(hist0, 0, 131072, stream);
    hipMemsetAsync((char*)hist0 + 131072, 0xAA, (size_t)512 * 131072, stream);
    hipMemsetAsync(hist1, 0, 131072, stream);
    hipMemsetAsync((char*)hist1 + 131072, 0xAA, (size_t)512 * 131072, stream);
    hipLaunchKernelGGL(prep_kernel, dim3(512), dim3(256), 0, stream, Wih, Whh, bih, bhh, wbf, bsum);
    hipLaunchKernelGGL(gemm_pre, dim3(1024), dim3(256), 0, stream,
                       wbf /*wih0*/, bsum, emb, x, (const u32*)nullptr, Xpre, 0);
    hipLaunchKernelGGL(rnn_fused, dim3(64), dim3(256), 0, stream,
                       wbf, bsum, Xpre, hist0, hist1, len, out);
  } else {
    // ---------- fallback: proven sequential two-pass flow ----------
    float* Xpre  = (float*)(ws);
    u32*   hist  = (u32*)(ws + 67108864);
    u16*   wbf   = (u16*)(ws + 134348800);
    float* bsum  = (float*)(ws + 136445952);

    hipMemsetAsync(hist, 0, 131072, stream);
    hipMemsetAsync((char*)hist + 131072, 0xAA, (size_t)512 * 131072, stream);
    hipLaunchKernelGGL(prep_kernel, dim3(512), dim3(256), 0, stream, Wih, Whh, bih, bhh, wbf, bsum);
    hipLaunchKernelGGL(gemm_pre, dim3(1024), dim3(256), 0, stream,
                       wbf, bsum, emb, x, (const u32*)nullptr, Xpre, 0);
    hipLaunchKernelGGL(rnn_pass, dim3(32), dim3(256), 0, stream,
                       wbf + 262144, Xpre, hist, len,
                       (float*)nullptr, out + 32768);
    hipLaunchKernelGGL(gemm_pre, dim3(1024), dim3(256), 0, stream,
                       wbf + 524288, bsum + 512, (const float*)nullptr, (const int*)nullptr,
                       hist, Xpre, 1);
    hipMemsetAsync((char*)hist + 131072, 0xAA, (size_t)512 * 131072, stream);
    hipLaunchKernelGGL(rnn_pass, dim3(32), dim3(256), 0, stream,
                       wbf + 786432, Xpre, hist, len,
                       out, out + 32768 + 512);
  }
}